// Round 4
// baseline (120.165 us; speedup 1.0000x reference)
//
#include <hip/hip_runtime.h>
#include <stdint.h>

#define B_ROWS 1024
#define FEAT   256
#define QSZ    32768
#define SHIFT  1024
#define QX     (QSZ - B_ROWS)   // 31744
#define NQB    256              // q-tiles of 128 (M dim)
#define NXB    8                // x-tiles of 128 (N dim)
#define MARGIN 20.0f            // fp8 scoring noise (~3 sigma) + key quantization, 6x headroom

typedef float v4f __attribute__((ext_vector_type(4)));
typedef int   v4i __attribute__((ext_vector_type(4)));
typedef int   v8i __attribute__((ext_vector_type(8)));

// ---------- packed score keys: orderable(m)[31:15] | j[14:0] ----------
__device__ __forceinline__ uint32_t key_flip(uint32_t u) {
    return u ^ ((uint32_t)((int32_t)u >> 31) | 0x80000000u);
}
__device__ __forceinline__ float key_m(uint32_t k) {
    uint32_t u = k & 0xFFFF8000u;
    u = (u & 0x80000000u) ? (u ^ 0x80000000u) : ~u;
    return __uint_as_float(u);
}
__device__ __forceinline__ void k2_insert(uint32_t& k1, uint32_t& k2, uint32_t key) {
    uint32_t hi = max(k1, key); k1 = min(k1, key); k2 = min(k2, hi);
}
__device__ __forceinline__ uint2 k2_merge(uint2 a, uint2 b) {
    uint32_t hi = max(a.x, b.x);
    uint2 r; r.x = min(a.x, b.x); r.y = min(min(a.y, b.y), hi);
    return r;
}

// ---------- exact-score top2 (float + index tie-break, matches top_k) ----------
struct Top2 { float m1; int j1; float m2; int j2; };
__device__ __forceinline__ bool better(float ma, int ja, float mb, int jb) {
    return (ma < mb) || (ma == mb && ja < jb);
}
__device__ __forceinline__ void t2_insert(Top2& t, float m, int j) {
    if (better(m, j, t.m1, t.j1)) { t.m2 = t.m1; t.j2 = t.j1; t.m1 = m; t.j1 = j; }
    else if (better(m, j, t.m2, t.j2)) { t.m2 = m; t.j2 = j; }
}

__device__ __forceinline__ const float* q_row_ptr(int j, const float* x, const float* queue) {
    return (j < QX) ? (queue + (size_t)(j + SHIFT) * FEAT) : (x + (size_t)(j - QX) * FEAT);
}

__device__ __forceinline__ void lds_load16(const void* g, void* l) {
    __builtin_amdgcn_global_load_lds(
        (const __attribute__((address_space(1))) uint32_t*)g,
        (__attribute__((address_space(3))) uint32_t*)l, 16, 0, 0);
}

// ---------- kernel 1: q_f8 (e4m3 row-major, x tail included) + q2 (f32) ----------
__global__ __launch_bounds__(256) void convert_kernel(const float* __restrict__ x,
                                                      const float* __restrict__ queue,
                                                      uint32_t* __restrict__ q_f8,
                                                      float* __restrict__ q2) {
    int wave = threadIdx.x >> 6, lane = threadIdx.x & 63;
    int j = blockIdx.x * 4 + wave;
    const float4* row = (const float4*)q_row_ptr(j, x, queue);
    float4 v = row[lane];
    float s = v.x * v.x + v.y * v.y + v.z * v.z + v.w * v.w;
#pragma unroll
    for (int off = 32; off; off >>= 1) s += __shfl_xor(s, off, 64);
    if (lane == 0) q2[j] = s;
    uint32_t u = __builtin_amdgcn_cvt_pk_fp8_f32(v.x, v.y, 0, false);   // bytes 0,1
    u = __builtin_amdgcn_cvt_pk_fp8_f32(v.z, v.w, u, true);             // bytes 2,3
    q_f8[(size_t)j * 64 + lane] = u;
}

// ---------- kernel 2: fp8 MFMA GEMM (unit MX scales), A=q rows (M), B=x rows (N) ----------
// 128x128 tile, K=256 in 2 chunks of 128; swizzled LDS (granule g' = g ^ (row&7)),
// identical conflict-free structure to the R3 bf16 kernel (measured SQ_LDS_BANK_CONFLICT ~0).
__global__ __launch_bounds__(256, 3) void nn_mfma(const uint8_t* __restrict__ q_f8,
                                                  const float* __restrict__ q2,
                                                  uint2* __restrict__ partials) {
    __shared__ uint8_t As[128 * 128];  // 16 KB  [row][swizzled 16B granules of 128B k-chunk]
    __shared__ uint8_t Bs[128 * 128];  // 16 KB
    __shared__ float sq2[128];
    __shared__ uint2 scr[128][2];

    const int t    = threadIdx.x;
    const int w    = t >> 6, lane = t & 63;
    const int wm   = w >> 1, wn = w & 1;
    const int quad = lane >> 4, l16 = lane & 15;
    const int gy   = blockIdx.x;  // q tile (rows of D)
    const int gx   = blockIdx.y;  // x tile (cols of D)

    const uint8_t* x_f8 = q_f8 + (size_t)QX * FEAT;

    if (t < 128) sq2[t] = q2[gy * 128 + t];

    v4f acc[4][4];
#pragma unroll
    for (int a = 0; a < 4; ++a)
#pragma unroll
        for (int b = 0; b < 4; ++b) acc[a][b] = (v4f)0.0f;

    const int srow = lane >> 3;
    const int sg   = (lane & 7) ^ srow;          // swizzled source granule (staging)
    const int gsw  = l16 & 7;
    const int g0   = (2 * quad) ^ gsw;            // swizzled frag granules (reading)
    const int g1   = (2 * quad + 1) ^ gsw;

    for (int c = 0; c < 2; ++c) {
        __syncthreads();
#pragma unroll
        for (int kk = 0; kk < 4; ++kk) {
            int row = w * 32 + kk * 8 + srow;
            const uint8_t* ga = q_f8 + (size_t)(gy * 128 + row) * FEAT + c * 128 + sg * 16;
            const uint8_t* gb = x_f8 + (size_t)(gx * 128 + row) * FEAT + c * 128 + sg * 16;
            lds_load16(ga, &As[(w * 32 + kk * 8) * 128]);
            lds_load16(gb, &Bs[(w * 32 + kk * 8) * 128]);
        }
        __syncthreads();
        const uint8_t* arow = As + (wm * 64 + l16) * 128;
        const uint8_t* brow = Bs + (wn * 64 + l16) * 128;
        v8i fa[4], fb[4];
#pragma unroll
        for (int tm = 0; tm < 4; ++tm) {
            v4i lo = *(const v4i*)(arow + tm * 2048 + g0 * 16);
            v4i hi = *(const v4i*)(arow + tm * 2048 + g1 * 16);
            fa[tm][0] = lo[0]; fa[tm][1] = lo[1]; fa[tm][2] = lo[2]; fa[tm][3] = lo[3];
            fa[tm][4] = hi[0]; fa[tm][5] = hi[1]; fa[tm][6] = hi[2]; fa[tm][7] = hi[3];
        }
#pragma unroll
        for (int tn = 0; tn < 4; ++tn) {
            v4i lo = *(const v4i*)(brow + tn * 2048 + g0 * 16);
            v4i hi = *(const v4i*)(brow + tn * 2048 + g1 * 16);
            fb[tn][0] = lo[0]; fb[tn][1] = lo[1]; fb[tn][2] = lo[2]; fb[tn][3] = lo[3];
            fb[tn][4] = hi[0]; fb[tn][5] = hi[1]; fb[tn][6] = hi[2]; fb[tn][7] = hi[3];
        }
#pragma unroll
        for (int tm = 0; tm < 4; ++tm)
#pragma unroll
            for (int tn = 0; tn < 4; ++tn)
                acc[tm][tn] = __builtin_amdgcn_mfma_scale_f32_16x16x128_f8f6f4(
                    fa[tm], fb[tn], acc[tm][tn],
                    0, 0,                     // cbsz: A fmt = FP8(e4m3), blgp: B fmt = FP8
                    0, 0x7F7F7F7F,            // opsel_a, scale_a = E8M0 1.0 per 32-block
                    0, 0x7F7F7F7F);           // opsel_b, scale_b
    }

    // ---- epilogue: keys = orderable(q2[row]-2*acc)|row; per-thread top2 per x-col ----
    float q2r[4][4];
#pragma unroll
    for (int tm = 0; tm < 4; ++tm) {
        v4f qq = *(const v4f*)&sq2[wm * 64 + tm * 16 + quad * 4];
#pragma unroll
        for (int r = 0; r < 4; ++r) q2r[tm][r] = qq[r];
    }
    const int jbase = gy * 128 + wm * 64 + quad * 4;

    uint2 best[4];
#pragma unroll
    for (int tn = 0; tn < 4; ++tn) {
        uint32_t k1 = 0xFFFFFFFFu, k2 = 0xFFFFFFFFu;
#pragma unroll
        for (int tm = 0; tm < 4; ++tm)
#pragma unroll
            for (int r = 0; r < 4; ++r) {
                float m = fmaf(-2.0f, acc[tm][tn][r], q2r[tm][r]);
                uint32_t u = key_flip(__float_as_uint(m));
                uint32_t key = (u & 0xFFFF8000u) | (uint32_t)(jbase + tm * 16 + r);
                k2_insert(k1, k2, key);
            }
#pragma unroll
        for (int mask = 16; mask <= 32; mask <<= 1) {
            uint32_t o1 = __shfl_xor(k1, mask, 64);
            uint32_t o2 = __shfl_xor(k2, mask, 64);
            uint32_t hi = max(k1, o1);
            k1 = min(k1, o1);
            k2 = min(min(k2, o2), hi);
        }
        best[tn] = make_uint2(k1, k2);
    }
    if (quad == 0) {
#pragma unroll
        for (int tn = 0; tn < 4; ++tn) scr[wn * 64 + tn * 16 + l16][wm] = best[tn];
    }
    __syncthreads();
    if (t < 128) {
        uint2 r = k2_merge(scr[t][0], scr[t][1]);
        partials[(size_t)(gx * 128 + t) * NQB + gy] = r;
    }
}

// ---------- kernel 3: single-wave cutoff + exact f32 rescore + gather ----------
__global__ __launch_bounds__(64) void nn_finalize(const float* __restrict__ x,
                                                  const float* __restrict__ queue,
                                                  const float* __restrict__ q2,
                                                  const uint2* __restrict__ partials,
                                                  float* __restrict__ out) {
    __shared__ int list[64];
    __shared__ int s_cnt;

    const int i = blockIdx.x, lane = threadIdx.x;
    if (lane == 0) s_cnt = 0;

    const uint2* p = partials + (size_t)i * NQB;
    uint2 mine[4];
#pragma unroll
    for (int u = 0; u < 4; ++u) mine[u] = p[lane + 64 * u];
    uint2 a = k2_merge(k2_merge(mine[0], mine[1]), k2_merge(mine[2], mine[3]));
#pragma unroll
    for (int mask = 1; mask <= 32; mask <<= 1) {
        uint2 o;
        o.x = __shfl_xor(a.x, mask, 64);
        o.y = __shfl_xor(a.y, mask, 64);
        a = k2_merge(a, o);
    }
    float cutf = key_m(a.y) + MARGIN;
    uint32_t kcut = key_flip(__float_as_uint(cutf)) | 0x7FFFu;

#pragma unroll
    for (int u = 0; u < 4; ++u) {
        if (mine[u].x <= kcut) list[atomicAdd(&s_cnt, 1) & 63] = (int)(mine[u].x & 0x7FFFu);
        if (mine[u].y <= kcut) list[atomicAdd(&s_cnt, 1) & 63] = (int)(mine[u].y & 0x7FFFu);
    }
    __syncthreads();  // single wave: compiler reordering fence for LDS
    int n = min(s_cnt, 64);

    float4 xv = ((const float4*)(x + (size_t)i * FEAT))[lane];
    Top2 bst;
    bst.m1 = __builtin_inff(); bst.j1 = 0x7FFFFFFF;
    bst.m2 = __builtin_inff(); bst.j2 = 0x7FFFFFFF;
    for (int c = 0; c < n; ++c) {
        int j = list[c];
        float4 qv = ((const float4*)q_row_ptr(j, x, queue))[lane];
        float s = qv.x * xv.x + qv.y * xv.y + qv.z * xv.z + qv.w * xv.w;
#pragma unroll
        for (int off = 32; off; off >>= 1) s += __shfl_xor(s, off, 64);
        float m = q2[j] - 2.0f * s;   // lane-uniform exact score
        t2_insert(bst, m, j);
    }
    int j2 = bst.j2;  // second-nearest (nearest is self)
    float4 o = ((const float4*)q_row_ptr(j2, x, queue))[lane];
    ((float4*)(out + (size_t)i * FEAT))[lane] = o;
}

extern "C" void kernel_launch(void* const* d_in, const int* in_sizes, int n_in,
                              void* d_out, int out_size, void* d_ws, size_t ws_size,
                              hipStream_t stream) {
    const float* x     = (const float*)d_in[0];
    const float* queue = (const float*)d_in[1];

    uint32_t* q_f8     = (uint32_t*)d_ws;                           // 8 MB
    float*    q2       = (float*)((char*)d_ws + (8u << 20));        // 128 KB
    uint2*    partials = (uint2*)((char*)d_ws + (9u << 20));        // 2 MB

    convert_kernel<<<QSZ / 4, 256, 0, stream>>>(x, queue, q_f8, q2);
    nn_mfma<<<dim3(NQB, NXB), 256, 0, stream>>>((const uint8_t*)q_f8, q2, partials);
    nn_finalize<<<B_ROWS, 64, 0, stream>>>(x, queue, q2, partials, (float*)d_out);
}

// Round 5
// 115.217 us; speedup vs baseline: 1.0429x; 1.0429x over previous
//
#include <hip/hip_runtime.h>
#include <stdint.h>

#define B_ROWS 1024
#define FEAT   256
#define QSZ    32768
#define SHIFT  1024
#define QX     (QSZ - B_ROWS)   // 31744
#define NQB    256              // partials per x-row (q-tiles of 128)
#define MARGIN 8.0f             // bf16 scoring noise + key quantization headroom

typedef float v4f __attribute__((ext_vector_type(4)));
typedef short v8s __attribute__((ext_vector_type(8)));

// ---------- packed score keys: orderable(m)[31:15] | j[14:0] ----------
__device__ __forceinline__ uint32_t key_flip(uint32_t u) {
    return u ^ ((uint32_t)((int32_t)u >> 31) | 0x80000000u);
}
__device__ __forceinline__ float key_m(uint32_t k) {
    uint32_t u = k & 0xFFFF8000u;
    u = (u & 0x80000000u) ? (u ^ 0x80000000u) : ~u;
    return __uint_as_float(u);
}
__device__ __forceinline__ void k2_insert(uint32_t& k1, uint32_t& k2, uint32_t key) {
    uint32_t hi = max(k1, key); k1 = min(k1, key); k2 = min(k2, hi);
}
__device__ __forceinline__ uint2 k2_merge(uint2 a, uint2 b) {
    uint32_t hi = max(a.x, b.x);
    uint2 r; r.x = min(a.x, b.x); r.y = min(min(a.y, b.y), hi);
    return r;
}

// ---------- exact-score top2 (float + index tie-break, matches top_k) ----------
struct Top2 { float m1; int j1; float m2; int j2; };
__device__ __forceinline__ bool better(float ma, int ja, float mb, int jb) {
    return (ma < mb) || (ma == mb && ja < jb);
}
__device__ __forceinline__ void t2_insert(Top2& t, float m, int j) {
    if (better(m, j, t.m1, t.j1)) { t.m2 = t.m1; t.j2 = t.j1; t.m1 = m; t.j1 = j; }
    else if (better(m, j, t.m2, t.j2)) { t.m2 = m; t.j2 = j; }
}

__device__ __forceinline__ const float* q_row_ptr(int j, const float* x, const float* queue) {
    return (j < QX) ? (queue + (size_t)(j + SHIFT) * FEAT) : (x + (size_t)(j - QX) * FEAT);
}

__device__ __forceinline__ unsigned short f2bf(float f) {  // round-to-nearest-even
    uint32_t u = __float_as_uint(f);
    uint32_t r = u + 0x7FFFu + ((u >> 16) & 1u);
    return (unsigned short)(r >> 16);
}

__device__ __forceinline__ void lds_load16(const void* g, void* l) {
    __builtin_amdgcn_global_load_lds(
        (const __attribute__((address_space(1))) uint32_t*)g,
        (__attribute__((address_space(3))) uint32_t*)l, 16, 0, 0);
}

// ---------- kernel 1: q_bf (bf16 row-major, x tail included) + q2 (f32) ----------
__global__ __launch_bounds__(256) void convert_kernel(const float* __restrict__ x,
                                                      const float* __restrict__ queue,
                                                      unsigned short* __restrict__ q_bf,
                                                      float* __restrict__ q2) {
    int wave = threadIdx.x >> 6, lane = threadIdx.x & 63;
    int j = blockIdx.x * 4 + wave;
    const float4* row = (const float4*)q_row_ptr(j, x, queue);
    float4 v = row[lane];
    float s = v.x * v.x + v.y * v.y + v.z * v.z + v.w * v.w;
#pragma unroll
    for (int off = 32; off; off >>= 1) s += __shfl_xor(s, off, 64);
    if (lane == 0) q2[j] = s;
    ushort4 h;
    h.x = f2bf(v.x); h.y = f2bf(v.y); h.z = f2bf(v.z); h.w = f2bf(v.w);
    ((ushort4*)q_bf)[(size_t)j * 64 + lane] = h;
}

// ---------- kernel 2: bf16 MFMA GEMM, 256M(q) x 128N(x) per block ----------
// Two 128-row q-tiles per block share the staged x-tile chunk: 64 MFMA per barrier,
// -25% staging. XCD-banded gyU so each XCD's q-band (2 MB) is L2-resident.
// Swizzled LDS (granule g' = g ^ (row&7)) — conflict-free (measured R2/R3 ~0).
__global__ __launch_bounds__(256, 2) void nn_mfma(const unsigned short* __restrict__ q_bf,
                                                  const float* __restrict__ q2,
                                                  uint2* __restrict__ partials) {
    __shared__ unsigned short As0[128 * 64];  // 16 KB, q-tile h=0 chunk
    __shared__ unsigned short As1[128 * 64];  // 16 KB, q-tile h=1 chunk
    __shared__ unsigned short Bs[128 * 64];   // 16 KB, x-tile chunk
    __shared__ float sq2[256];

    const int t    = threadIdx.x;
    const int w    = t >> 6, lane = t & 63;
    const int wm   = w >> 1, wn = w & 1;
    const int quad = lane >> 4, l16 = lane & 15;

    // XCD-banded mapping (assumes round-robin dispatch; perf heuristic only)
    const int id  = blockIdx.x;          // 0..1023
    const int sub = id >> 3;             // 0..127
    const int gx  = sub & 7;             // x tile (N)
    const int gyU = (id & 7) * 16 + (sub >> 3);  // 0..127: 256-row q unit, banded per XCD

    const unsigned short* x_bf  = q_bf + (size_t)QX * FEAT;
    const unsigned short* aBase = q_bf + (size_t)gyU * 256 * FEAT;
    const unsigned short* bBase = x_bf + (size_t)gx * 128 * FEAT;

    sq2[t] = q2[gyU * 256 + t];

    v4f acc[2][4][4];
#pragma unroll
    for (int h = 0; h < 2; ++h)
#pragma unroll
        for (int a = 0; a < 4; ++a)
#pragma unroll
            for (int b = 0; b < 4; ++b) acc[h][a][b] = (v4f)0.0f;

    const int srow = lane >> 3;
    const int sg   = (lane & 7) ^ srow;  // swizzled source granule

    // stage chunk 0 (fresh LDS — no barrier needed before)
#pragma unroll
    for (int kk = 0; kk < 4; ++kk) {
        int row = w * 32 + kk * 8 + srow;
        int ldsrow = (w * 32 + kk * 8) * 64;
        lds_load16(aBase + (size_t)row * FEAT + sg * 8,         &As0[ldsrow]);
        lds_load16(aBase + (size_t)(row + 128) * FEAT + sg * 8, &As1[ldsrow]);
        lds_load16(bBase + (size_t)row * FEAT + sg * 8,         &Bs[ldsrow]);
    }

    for (int c = 0; c < 4; ++c) {
        __syncthreads();  // vmcnt drained by barrier semantics -> staging visible
#pragma unroll
        for (int ks = 0; ks < 2; ++ks) {
            v8s fa0[4], fa1[4], fb[4];
            const int goff  = (((ks * 4 + quad) ^ (l16 & 7)) << 4);
            const int abase = (wm * 64 + l16) * 128 + goff;
            const int bbase = (wn * 64 + l16) * 128 + goff;
#pragma unroll
            for (int tm = 0; tm < 4; ++tm) {
                fa0[tm] = *(const v8s*)((const char*)As0 + abase + tm * 2048);
                fa1[tm] = *(const v8s*)((const char*)As1 + abase + tm * 2048);
            }
#pragma unroll
            for (int tn = 0; tn < 4; ++tn)
                fb[tn] = *(const v8s*)((const char*)Bs + bbase + tn * 2048);
#pragma unroll
            for (int tm = 0; tm < 4; ++tm)
#pragma unroll
                for (int tn = 0; tn < 4; ++tn) {
                    acc[0][tm][tn] = __builtin_amdgcn_mfma_f32_16x16x32_bf16(fa0[tm], fb[tn], acc[0][tm][tn], 0, 0, 0);
                    acc[1][tm][tn] = __builtin_amdgcn_mfma_f32_16x16x32_bf16(fa1[tm], fb[tn], acc[1][tm][tn], 0, 0, 0);
                }
        }
        __syncthreads();  // all frag reads of chunk c done
        if (c < 3) {
#pragma unroll
            for (int kk = 0; kk < 4; ++kk) {
                int row = w * 32 + kk * 8 + srow;
                int ldsrow = (w * 32 + kk * 8) * 64;
                lds_load16(aBase + (size_t)row * FEAT + (c + 1) * 64 + sg * 8,         &As0[ldsrow]);
                lds_load16(aBase + (size_t)(row + 128) * FEAT + (c + 1) * 64 + sg * 8, &As1[ldsrow]);
                lds_load16(bBase + (size_t)row * FEAT + (c + 1) * 64 + sg * 8,         &Bs[ldsrow]);
            }
        }
    }

    // ---- epilogue: keys = orderable(q2[row]-2*acc)|row; top2 per x-col, both q-halves ----
    uint2* scr = (uint2*)As0;  // overlay: [h][x-col 0..127][wm 0..1] = 4 KB
#pragma unroll
    for (int h = 0; h < 2; ++h) {
        float q2r[4][4];
#pragma unroll
        for (int tm = 0; tm < 4; ++tm)
#pragma unroll
            for (int r = 0; r < 4; ++r)
                q2r[tm][r] = sq2[h * 128 + wm * 64 + tm * 16 + quad * 4 + r];
        const int jbase = gyU * 256 + h * 128 + wm * 64 + quad * 4;

#pragma unroll
        for (int tn = 0; tn < 4; ++tn) {
            uint32_t k1 = 0xFFFFFFFFu, k2 = 0xFFFFFFFFu;
#pragma unroll
            for (int tm = 0; tm < 4; ++tm)
#pragma unroll
                for (int r = 0; r < 4; ++r) {
                    float m = fmaf(-2.0f, acc[h][tm][tn][r], q2r[tm][r]);
                    uint32_t u = key_flip(__float_as_uint(m));
                    uint32_t key = (u & 0xFFFF8000u) | (uint32_t)(jbase + tm * 16 + r);
                    k2_insert(k1, k2, key);
                }
#pragma unroll
            for (int mask = 16; mask <= 32; mask <<= 1) {
                uint32_t o1 = __shfl_xor(k1, mask, 64);
                uint32_t o2 = __shfl_xor(k2, mask, 64);
                uint32_t hi = max(k1, o1);
                k1 = min(k1, o1);
                k2 = min(min(k2, o2), hi);
            }
            if (quad == 0)
                scr[(h * 128 + wn * 64 + tn * 16 + l16) * 2 + wm] = make_uint2(k1, k2);
        }
    }
    __syncthreads();
    if (t < 128) {
#pragma unroll
        for (int h = 0; h < 2; ++h) {
            uint2 r = k2_merge(scr[(h * 128 + t) * 2], scr[(h * 128 + t) * 2 + 1]);
            partials[(size_t)(gx * 128 + t) * NQB + (gyU * 2 + h)] = r;
        }
    }
}

// ---------- kernel 3: single-wave cutoff + exact f32 rescore + gather ----------
__global__ __launch_bounds__(64) void nn_finalize(const float* __restrict__ x,
                                                  const float* __restrict__ queue,
                                                  const float* __restrict__ q2,
                                                  const uint2* __restrict__ partials,
                                                  float* __restrict__ out) {
    __shared__ int list[64];
    __shared__ int s_cnt;

    const int i = blockIdx.x, lane = threadIdx.x;
    if (lane == 0) s_cnt = 0;

    const uint2* p = partials + (size_t)i * NQB;
    uint2 mine[4];
#pragma unroll
    for (int u = 0; u < 4; ++u) mine[u] = p[lane + 64 * u];
    uint2 a = k2_merge(k2_merge(mine[0], mine[1]), k2_merge(mine[2], mine[3]));
#pragma unroll
    for (int mask = 1; mask <= 32; mask <<= 1) {
        uint2 o;
        o.x = __shfl_xor(a.x, mask, 64);
        o.y = __shfl_xor(a.y, mask, 64);
        a = k2_merge(a, o);
    }
    float cutf = key_m(a.y) + MARGIN;
    uint32_t kcut = key_flip(__float_as_uint(cutf)) | 0x7FFFu;

#pragma unroll
    for (int u = 0; u < 4; ++u) {
        if (mine[u].x <= kcut) list[atomicAdd(&s_cnt, 1) & 63] = (int)(mine[u].x & 0x7FFFu);
        if (mine[u].y <= kcut) list[atomicAdd(&s_cnt, 1) & 63] = (int)(mine[u].y & 0x7FFFu);
    }
    __syncthreads();
    int n = min(s_cnt, 64);

    float4 xv = ((const float4*)(x + (size_t)i * FEAT))[lane];
    Top2 bst;
    bst.m1 = __builtin_inff(); bst.j1 = 0x7FFFFFFF;
    bst.m2 = __builtin_inff(); bst.j2 = 0x7FFFFFFF;
    for (int c = 0; c < n; ++c) {
        int j = list[c];
        float4 qv = ((const float4*)q_row_ptr(j, x, queue))[lane];
        float s = qv.x * xv.x + qv.y * xv.y + qv.z * xv.z + qv.w * xv.w;
#pragma unroll
        for (int off = 32; off; off >>= 1) s += __shfl_xor(s, off, 64);
        float m = q2[j] - 2.0f * s;   // lane-uniform exact score
        t2_insert(bst, m, j);
    }
    int j2 = bst.j2;  // second-nearest (nearest is self)
    float4 o = ((const float4*)q_row_ptr(j2, x, queue))[lane];
    ((float4*)(out + (size_t)i * FEAT))[lane] = o;
}

extern "C" void kernel_launch(void* const* d_in, const int* in_sizes, int n_in,
                              void* d_out, int out_size, void* d_ws, size_t ws_size,
                              hipStream_t stream) {
    const float* x     = (const float*)d_in[0];
    const float* queue = (const float*)d_in[1];

    unsigned short* q_bf     = (unsigned short*)d_ws;                    // 16 MB
    float*          q2       = (float*)((char*)d_ws + (16u << 20));      // 128 KB
    uint2*          partials = (uint2*)((char*)d_ws + (17u << 20));      // 2 MB

    convert_kernel<<<QSZ / 4, 256, 0, stream>>>(x, queue, q_bf, q2);
    nn_mfma<<<1024, 256, 0, stream>>>(q_bf, q2, partials);
    nn_finalize<<<B_ROWS, 64, 0, stream>>>(x, queue, q2, partials, (float*)d_out);
}